// Round 4
// baseline (181.099 us; speedup 1.0000x reference)
//
#include <hip/hip_runtime.h>

// Problem constants (match reference file)
constexpr int Dv = 160, Hv = 192, Wv = 160;
constexpr int NN = Dv * Hv * Wv;  // 4,915,200 voxels

// Full-row tiles: TW = whole x extent -> every streaming access (flow2 read,
// out write, src stage) is long-contiguous (5-8 KB per block-row, 1 KB per
// wave-instruction), matching the 6.3 TB/s copy-bench access pattern.
// Theory: the ~3 TB/s plateau of rounds 0-3 is DRAM burst-granularity loss
// from 128 B fragments at 640 B stride; this removes it.
constexpr int TW = 160, TH = 8, TD = 4;   // grid (1, 24, 40) = 960 blocks
// LDS support tile: full x rows (no x halo needed - clamp + zero weights
// handle x OOB inside the tile), y halo [-2,+4), z halo [-2,+4).
constexpr int SX = 160, SY = 13, SZ = 9;
constexpr int SLEN = SX * SY * SZ;            // 18720 floats
constexpr int SVEC = SLEN / 4;                // 4680 16B segments
constexpr int SITER = (SVEC + 255) / 256;     // 19 staging iterations
constexpr int SPAD = SITER * 256 * 4;         // 19456 floats = 76 KB -> 2 blk/CU
constexpr int SROW = SX / 4;                  // 40 segments per row
constexpr int SPLANE = SY * SROW;             // 520 segments per z-plane
constexpr int NG = TW * TH * TD / 4;          // 1280 float4 voxel-groups
constexpr int KSTEPS = NG / 256;              // 5 groups per thread

// Trilinear sample of 3-channel flow1 at quirk-unnormalized coords:
// in-bounds only near the (0,0,0) corner, so this is execz-skipped for
// essentially every wave.
__device__ __forceinline__ void tri3_rare(const float* __restrict__ v,
                                          float gx, float gy, float gz,
                                          float& o0, float& o1, float& o2) {
  o0 = 0.0f; o1 = 0.0f; o2 = 0.0f;
  float ix = ((gx + 1.0f) * (float)Wv - 1.0f) * 0.5f;
  float iy = ((gy + 1.0f) * (float)Hv - 1.0f) * 0.5f;
  float iz = ((gz + 1.0f) * (float)Dv - 1.0f) * 0.5f;
  float fx = floorf(ix), fy = floorf(iy), fz = floorf(iz);
  int x0 = (int)fx, y0 = (int)fy, z0 = (int)fz;
  if (x0 < -1 || x0 >= Wv || y0 < -1 || y0 >= Hv || z0 < -1 || z0 >= Dv)
    return;  // entire 2x2x2 support OOB -> zeros
  float wx = ix - fx, wy = iy - fy, wz = iz - fz;
#pragma unroll
  for (int c = 0; c < 8; ++c) {
    const int dz = (c >> 2) & 1, dy = (c >> 1) & 1, dx = c & 1;
    int zi = z0 + dz, yi = y0 + dy, xi = x0 + dx;
    if ((unsigned)zi < (unsigned)Dv && (unsigned)yi < (unsigned)Hv &&
        (unsigned)xi < (unsigned)Wv) {
      float wgt = (dz ? wz : 1.0f - wz) * (dy ? wy : 1.0f - wy) *
                  (dx ? wx : 1.0f - wx);
      int lin = (zi * Hv + yi) * Wv + xi;
      o0 += wgt * v[lin];
      o1 += wgt * v[NN + lin];
      o2 += wgt * v[2 * NN + lin];
    }
  }
}

__global__ __launch_bounds__(256)
void st_rowtile_kernel(const float* __restrict__ src,
                       const float* __restrict__ flow1,
                       const float* __restrict__ flow2,
                       const float* __restrict__ rfp,
                       float* __restrict__ out) {
  __shared__ float tile[SPAD];

  const int tid = threadIdx.x;
  const int by0 = blockIdx.y * TH;   // h origin
  const int bz0 = blockIdx.z * TD;   // d origin
  const float rf = rfp[0];

  // ---- async global->LDS stage (16B wide, 19 iterations) ----
  // Tile rows ARE full global rows; per z-plane the 13 staged rows are a
  // single 8320B contiguous run (modulo y-edge clamping). Clamped halo rows
  // duplicate in-bounds rows; their values only ever meet zero weights.
  const int byo = by0 - 2, bzo = bz0 - 2;
#pragma unroll
  for (int i = 0; i < SITER; ++i) {
    int s = tid + i * 256;
    s = (i == SITER - 1) ? min(s, SVEC - 1) : s;
    int tz = s / SPLANE;
    int r = s - tz * SPLANE;
    int ty = r / SROW;
    int tx4 = (r - ty * SROW) * 4;
    int gy = min(max(byo + ty, 0), Hv - 1);
    int gz = min(max(bzo + tz, 0), Dv - 1);
    int g = (gz * Hv + gy) * Wv + tx4;      // 16B-aligned
    __builtin_amdgcn_global_load_lds(
        (const __attribute__((address_space(1))) void*)(src + g),
        (__attribute__((address_space(3))) void*)(tile + s * 4), 16, 0, 0);
  }

  // ---- per-k geometry + vectorized flow2 prefetch (15 x dwordx4) ----
  // Voxel-group g = tid + 256k covers the (d,h,w) tile flattened so that a
  // wave's 64 lanes read/write 1KB-contiguous runs.
  int idxK[KSTEPS], wK[KSTEPS];
  float dfK[KSTEPS], hfK[KSTEPS];
#pragma unroll
  for (int k = 0; k < KSTEPS; ++k) {
    int g = tid + k * 256;
    int dzl = g / (TH * SROW);               // g / 320
    int rem = g - dzl * (TH * SROW);
    int hl = rem / SROW;                     // rem / 40
    int wg = (rem - hl * SROW) * 4;
    int d = bz0 + dzl, h = by0 + hl;
    wK[k] = wg;
    dfK[k] = (float)d;
    hfK[k] = (float)h;
    idxK[k] = (d * Hv + h) * Wv + wg;        // 16B-aligned
  }
  float4 f2d4[KSTEPS], f2h4[KSTEPS], f2w4[KSTEPS];
#pragma unroll
  for (int k = 0; k < KSTEPS; ++k) {
    f2d4[k] = *(const float4*)(flow2 + idxK[k]);
    f2h4[k] = *(const float4*)(flow2 + NN + idxK[k]);
    f2w4[k] = *(const float4*)(flow2 + 2 * NN + idxK[k]);
  }
  __syncthreads();  // drains vmcnt for the LDS stage (+ flow2 prefetch)

  constexpr float KX = (float)Wv / (float)(Wv - 1);
  constexpr float KY = (float)Hv / (float)(Hv - 1);
  constexpr float KZ = (float)Dv / (float)(Dv - 1);

#pragma unroll
  for (int k = 0; k < KSTEPS; ++k) {
    const float df = dfK[k];
    const float hf = hfK[k];
    const int idx = idxK[k];

    float4 def, ofd4, ofh4, ofw4;
#pragma unroll
    for (int j = 0; j < 4; ++j) {
      const float wf = (float)(wK[k] + j);
      const float f2dv = (&f2d4[k].x)[j];
      const float f2hv = (&f2h4[k].x)[j];
      const float f2wv = (&f2w4[k].x)[j];

      // grid2 (x,y,z) = (w + rf*f2w, h + rf*f2h, d + rf*f2d) [NOT normalized]
      float a0, a1, a2;  // flow1 warped (d,h,w channels)
      tri3_rare(flow1, wf + rf * f2wv, hf + rf * f2hv, df + rf * f2dv,
                a0, a1, a2);

      float of_d = a0 + f2dv;
      float of_h = a1 + f2hv;
      float of_w = a2 + f2wv;
      (&ofd4.x)[j] = of_d;
      (&ofh4.x)[j] = of_h;
      (&ofw4.x)[j] = of_w;

      // src sample coords (algebraically simplified, align_corners=False):
      // ix = (w + rf*of_w) * W/(W-1) - 0.5, etc.
      float ix = (wf + rf * of_w) * KX - 0.5f;
      float iy = (hf + rf * of_h) * KY - 0.5f;
      float iz = (df + rf * of_d) * KZ - 0.5f;

      float fx = floorf(ix), fy = floorf(iy), fz = floorf(iz);
      float wx = ix - fx, wy = iy - fy, wz = iz - fz;
      int x0 = (int)fx, y0 = (int)fy, z0 = (int)fz;

      // zeros-padding validity -> per-axis weights
      float wx0 = ((unsigned)x0 < (unsigned)Wv) ? (1.0f - wx) : 0.0f;
      float wx1 = ((unsigned)(x0 + 1) < (unsigned)Wv) ? wx : 0.0f;
      float wy0 = ((unsigned)y0 < (unsigned)Hv) ? (1.0f - wy) : 0.0f;
      float wy1 = ((unsigned)(y0 + 1) < (unsigned)Hv) ? wy : 0.0f;
      float wz0 = ((unsigned)z0 < (unsigned)Dv) ? (1.0f - wz) : 0.0f;
      float wz1 = ((unsigned)(z0 + 1) < (unsigned)Dv) ? wz : 0.0f;

      // x handled entirely by clamp + zero weights (full row is in tile)
      int xa0 = min(max(x0, 0), Wv - 1), xa1 = min(max(x0 + 1, 0), Wv - 1);

      int tyi = y0 - byo, tzi = z0 - bzo;
      bool fast = ((unsigned)tyi <= (unsigned)(SY - 2)) &
                  ((unsigned)tzi <= (unsigned)(SZ - 2));

      float v000, v001, v010, v011, v100, v101, v110, v111;
      if (fast) {
        int rb = (tzi * SY + tyi) * SX;
        v000 = tile[rb + xa0];
        v001 = tile[rb + xa1];
        v010 = tile[rb + SX + xa0];
        v011 = tile[rb + SX + xa1];
        v100 = tile[rb + SY * SX + xa0];
        v101 = tile[rb + SY * SX + xa1];
        v110 = tile[rb + SY * SX + SX + xa0];
        v111 = tile[rb + SY * SX + SX + xa1];
      } else {
        // rare (~1e-6/voxel): y/z out of halo -> clamped global gather
        int ya0 = min(max(y0, 0), Hv - 1), ya1 = min(max(y0 + 1, 0), Hv - 1);
        int za0 = min(max(z0, 0), Dv - 1), za1 = min(max(z0 + 1, 0), Dv - 1);
        int r00 = (za0 * Hv + ya0) * Wv;
        int r01 = (za0 * Hv + ya1) * Wv;
        int r10 = (za1 * Hv + ya0) * Wv;
        int r11 = (za1 * Hv + ya1) * Wv;
        v000 = src[r00 + xa0]; v001 = src[r00 + xa1];
        v010 = src[r01 + xa0]; v011 = src[r01 + xa1];
        v100 = src[r10 + xa0]; v101 = src[r10 + xa1];
        v110 = src[r11 + xa0]; v111 = src[r11 + xa1];
      }

      float c00 = v000 * wx0 + v001 * wx1;
      float c01 = v010 * wx0 + v011 * wx1;
      float c10 = v100 * wx0 + v101 * wx1;
      float c11 = v110 * wx0 + v111 * wx1;
      float c0 = c00 * wy0 + c01 * wy1;
      float c1 = c10 * wy0 + c11 * wy1;
      (&def.x)[j] = c0 * wz0 + c1 * wz1;
    }

    // ---- vectorized stores: 4 x dwordx4 per k-group (1KB/wave/channel) ----
    *(float4*)(out + idx) = def;
    *(float4*)(out + NN + idx) = ofd4;
    *(float4*)(out + 2 * NN + idx) = ofh4;
    *(float4*)(out + 3 * NN + idx) = ofw4;
  }
}

extern "C" void kernel_launch(void* const* d_in, const int* in_sizes, int n_in,
                              void* d_out, int out_size, void* d_ws, size_t ws_size,
                              hipStream_t stream) {
  const float* src   = (const float*)d_in[0];
  const float* flow1 = (const float*)d_in[1];
  const float* flow2 = (const float*)d_in[2];
  const float* rfp   = (const float*)d_in[3];
  float* out = (float*)d_out;

  dim3 grid(1, Hv / TH, Dv / TD);  // 1 x 24 x 40 = 960 blocks
  hipLaunchKernelGGL(st_rowtile_kernel, grid, dim3(256), 0, stream,
                     src, flow1, flow2, rfp, out);
}